// Round 2
// baseline (624.290 us; speedup 1.0000x reference)
//
#include <hip/hip_runtime.h>

// Problem constants
#define BB 16
#define CC 128
#define PP 512
#define TT 32
#define HH 2
#define DD 64
#define EE 2048        // D*T
#define NPIX 16384     // P*T
#define SCALE 0.125f   // D^-0.5

typedef _Float16 f16_t;
typedef _Float16 f16x8_t __attribute__((ext_vector_type(8)));
typedef float    f32x4_t __attribute__((ext_vector_type(4)));

// ---------------------------------------------------------------------------
// Shared GEMM core: C(128x128 block) = A[M x K] @ Bt[N x K]^T, fp16 inputs,
// fp32 accum. 256 threads = 4 waves, each wave computes 64x64 (4x4 grid of
// 16x16x32 MFMA tiles). Both operands are K-contiguous per row: each fragment
// load is a single 16B load per lane.
// MFMA lane mapping (HW-verified): A[m=lane&15][k=quad*8+j],
// B[k=quad*8+j][n=lane&15], D[row=quad*4+reg][col=lane&15].
// ---------------------------------------------------------------------------
__device__ __forceinline__ void gemm_bt_core(const f16_t* __restrict__ A, int lda,
                                             const f16_t* __restrict__ Bt, int ldb,
                                             int K, int m_base, int n_base,
                                             int quad, int l16,
                                             f32x4_t acc[4][4])
{
    const f16_t* ap[4];
    const f16_t* bp[4];
#pragma unroll
    for (int i = 0; i < 4; ++i) {
        ap[i] = A  + (size_t)(m_base + i * 16 + l16) * lda + quad * 8;
        bp[i] = Bt + (size_t)(n_base + i * 16 + l16) * ldb + quad * 8;
    }
    for (int k0 = 0; k0 < K; k0 += 32) {
        f16x8_t af[4], bfr[4];
#pragma unroll
        for (int i = 0; i < 4; ++i) af[i]  = *(const f16x8_t*)(ap[i] + k0);
#pragma unroll
        for (int i = 0; i < 4; ++i) bfr[i] = *(const f16x8_t*)(bp[i] + k0);
#pragma unroll
        for (int mi = 0; mi < 4; ++mi)
#pragma unroll
            for (int ni = 0; ni < 4; ++ni)
                acc[mi][ni] = __builtin_amdgcn_mfma_f32_16x16x32_f16(
                    af[mi], bfr[ni], acc[mi][ni], 0, 0, 0);
    }
}

// ---------------------------------------------------------------------------
// Kernel 1: QKV projection.
// Y[o][pix] = sum_c W[o][c] * x[b][c][pix] + bias[o], o in [s*128, s*128+128)
// A = W rows (fp32, k-contiguous, convert to fp16), B = x columns (fp32,
// c-strided: 8 dword loads per fragment, coalesced across lanes per c).
// Output: q/k/v fp16 at [b][h][p][e], e = d*32 + t.
// grid: x = 3*128 (s fastest for x-tile L2 reuse), y = B. block 256.
// ---------------------------------------------------------------------------
__global__ __launch_bounds__(256) void proj_kernel(const float* __restrict__ x,
                                                   const float* __restrict__ W,
                                                   const float* __restrict__ bias,
                                                   f16_t* __restrict__ q,
                                                   f16_t* __restrict__ k,
                                                   f16_t* __restrict__ v)
{
    const int b    = blockIdx.y;
    const int s    = blockIdx.x % 3;
    const int pt   = blockIdx.x / 3;
    const int tid  = threadIdx.x;
    const int lane = tid & 63;
    const int wave = tid >> 6;
    const int wm   = wave & 1, wn = wave >> 1;
    const int quad = lane >> 4, l16 = lane & 15;
    const int pix_base = pt * 128 + wn * 64;
    const int m_base   = wm * 64;   // o_loc base within the 128-wide s slice

    const float* xb = x + (size_t)b * CC * NPIX;

    f32x4_t acc[4][4];
#pragma unroll
    for (int i = 0; i < 4; ++i)
#pragma unroll
        for (int j = 0; j < 4; ++j) acc[i][j] = (f32x4_t){0.f, 0.f, 0.f, 0.f};

#pragma unroll
    for (int k0 = 0; k0 < CC; k0 += 32) {
        const int kq = k0 + quad * 8;
        f16x8_t af[4], bfr[4];
#pragma unroll
        for (int mi = 0; mi < 4; ++mi) {
            const int o = s * 128 + m_base + mi * 16 + l16;
            const float* wp = W + o * CC + kq;
            const float4 w0 = *(const float4*)wp;
            const float4 w1 = *(const float4*)(wp + 4);
            f16x8_t t;
            t[0] = (_Float16)w0.x; t[1] = (_Float16)w0.y;
            t[2] = (_Float16)w0.z; t[3] = (_Float16)w0.w;
            t[4] = (_Float16)w1.x; t[5] = (_Float16)w1.y;
            t[6] = (_Float16)w1.z; t[7] = (_Float16)w1.w;
            af[mi] = t;
        }
#pragma unroll
        for (int ni = 0; ni < 4; ++ni) {
            const int pix = pix_base + ni * 16 + l16;
            const float* xp = xb + (size_t)kq * NPIX + pix;
            f16x8_t t;
#pragma unroll
            for (int j = 0; j < 8; ++j) t[j] = (_Float16)xp[(size_t)j * NPIX];
            bfr[ni] = t;
        }
#pragma unroll
        for (int mi = 0; mi < 4; ++mi)
#pragma unroll
            for (int ni = 0; ni < 4; ++ni)
                acc[mi][ni] = __builtin_amdgcn_mfma_f32_16x16x32_f16(
                    af[mi], bfr[ni], acc[mi][ni], 0, 0, 0);
    }

    f16_t* dst = (s == 0) ? q : (s == 1) ? k : v;
#pragma unroll
    for (int mi = 0; mi < 4; ++mi) {
#pragma unroll
        for (int r = 0; r < 4; ++r) {
            const int o_loc = m_base + mi * 16 + quad * 4 + r;
            const int o     = s * 128 + o_loc;
            const float bv  = bias[o];
            const int h = o_loc >> 6, d = o_loc & 63;
#pragma unroll
            for (int ni = 0; ni < 4; ++ni) {
                const int pix = pix_base + ni * 16 + l16;
                const int p = pix >> 5, t = pix & 31;
                const size_t addr =
                    ((size_t)((b * HH + h) * PP + p)) * EE + d * TT + t;
                dst[addr] = (_Float16)(acc[mi][ni][r] + bv);
            }
        }
    }
}

// ---------------------------------------------------------------------------
// Kernel 2: transpose v [bh][p][e] -> vt [bh][e][p] (64x64 LDS tiles).
// grid: x = (512/64)*(2048/64) = 256 tiles, y = 32 bh. block 256.
// ---------------------------------------------------------------------------
__global__ __launch_bounds__(256) void vpose_kernel(const f16_t* __restrict__ v,
                                                    f16_t* __restrict__ vt)
{
    __shared__ unsigned short lds[64][65];
    const int bh   = blockIdx.y;
    const int tile = blockIdx.x;
    const int e0 = (tile & 31) * 64;
    const int p0 = (tile >> 5) * 64;
    const int tid = threadIdx.x;
    const int r0 = tid >> 6;    // 0..3
    const int cc = tid & 63;
    const f16_t* vb  = v  + (size_t)bh * PP * EE;
    f16_t*       vtb = vt + (size_t)bh * EE * PP;
#pragma unroll
    for (int it = 0; it < 16; ++it) {
        const int pl = it * 4 + r0;
        lds[pl][cc] = __builtin_bit_cast(unsigned short,
                          vb[(size_t)(p0 + pl) * EE + e0 + cc]);
    }
    __syncthreads();
#pragma unroll
    for (int it = 0; it < 16; ++it) {
        const int el = it * 4 + r0;
        vtb[(size_t)(e0 + el) * PP + p0 + cc] =
            __builtin_bit_cast(_Float16, lds[cc][el]);
    }
}

// ---------------------------------------------------------------------------
// Kernel 3: S = SCALE * Q @ K^T per (b,h). M=N=512, K=2048.
// grid: x = 4 mt * 4 nt = 16, y = 32 bh. block 256.
// ---------------------------------------------------------------------------
__global__ __launch_bounds__(256) void qk_kernel(const f16_t* __restrict__ q,
                                                 const f16_t* __restrict__ k,
                                                 float* __restrict__ S)
{
    const int bh = blockIdx.y;
    const int mt = blockIdx.x & 3, nt = blockIdx.x >> 2;
    const int tid  = threadIdx.x;
    const int lane = tid & 63;
    const int wave = tid >> 6;
    const int wm = wave & 1, wn = wave >> 1;
    const int quad = lane >> 4, l16 = lane & 15;

    f32x4_t acc[4][4];
#pragma unroll
    for (int i = 0; i < 4; ++i)
#pragma unroll
        for (int j = 0; j < 4; ++j) acc[i][j] = (f32x4_t){0.f, 0.f, 0.f, 0.f};

    const f16_t* qb = q + (size_t)bh * PP * EE;
    const f16_t* kb = k + (size_t)bh * PP * EE;
    gemm_bt_core(qb, EE, kb, EE, EE,
                 mt * 128 + wm * 64, nt * 128 + wn * 64, quad, l16, acc);

    float* Sb = S + (size_t)bh * PP * PP;
#pragma unroll
    for (int mi = 0; mi < 4; ++mi)
#pragma unroll
        for (int r = 0; r < 4; ++r) {
            const int row = mt * 128 + wm * 64 + mi * 16 + quad * 4 + r;
#pragma unroll
            for (int ni = 0; ni < 4; ++ni) {
                const int col = nt * 128 + wn * 64 + ni * 16 + l16;
                Sb[(size_t)row * PP + col] = acc[mi][ni][r] * SCALE;
            }
        }
}

// ---------------------------------------------------------------------------
// Kernel 4: row softmax over S (16384 rows of 512), writing normalized P as
// fp16 overlaid into S's storage: P row i lives at the start of S row i
// (row pitch = 1024 fp16 elements = 2048 B). One wave per row.
// __syncthreads() between load and store phases hard-orders the aliased
// float-load / fp16-store (TBAA guard).
// ---------------------------------------------------------------------------
__global__ __launch_bounds__(256) void softmax_kernel(float* __restrict__ S)
{
    const int tid  = threadIdx.x;
    const int wave = tid >> 6;
    const int lane = tid & 63;
    const int row  = blockIdx.x * 4 + wave;           // 0..16383 (bh*512 + i)
    float* rp = S + (size_t)row * PP;

    const float4 a = *(const float4*)(rp + lane * 8);
    const float4 b = *(const float4*)(rp + lane * 8 + 4);

    float m = fmaxf(fmaxf(fmaxf(a.x, a.y), fmaxf(a.z, a.w)),
                    fmaxf(fmaxf(b.x, b.y), fmaxf(b.z, b.w)));
#pragma unroll
    for (int off = 1; off < 64; off <<= 1) m = fmaxf(m, __shfl_xor(m, off, 64));

    float e[8];
    e[0] = expf(a.x - m); e[1] = expf(a.y - m);
    e[2] = expf(a.z - m); e[3] = expf(a.w - m);
    e[4] = expf(b.x - m); e[5] = expf(b.y - m);
    e[6] = expf(b.z - m); e[7] = expf(b.w - m);

    float sum = e[0] + e[1] + e[2] + e[3] + e[4] + e[5] + e[6] + e[7];
#pragma unroll
    for (int off = 1; off < 64; off <<= 1) sum += __shfl_xor(sum, off, 64);
    const float inv = 1.0f / sum;

    __syncthreads();   // order the fp16 stores after all float loads

    f16_t* prow = (f16_t*)rp;
    f16x8_t o;
#pragma unroll
    for (int j = 0; j < 8; ++j) o[j] = (_Float16)(e[j] * inv);
    *(f16x8_t*)(prow + lane * 8) = o;
}

// ---------------------------------------------------------------------------
// Kernel 5: O = P @ V per (b,h), written straight to out fp32 (b,c,p,t).
// A = P (pitch 1024 fp16), B = vt [e][p]. M=512 (p), N=2048 (e), K=512.
// grid: x = 4 mt * 16 nt = 64, y = 32 bh. block 256.
// ---------------------------------------------------------------------------
__global__ __launch_bounds__(256) void pv_kernel(const f16_t* __restrict__ Pm,
                                                 const f16_t* __restrict__ vt,
                                                 float* __restrict__ out)
{
    const int bh = blockIdx.y;
    const int mt = blockIdx.x & 3;     // p tile
    const int nt = blockIdx.x >> 2;    // e tile
    const int tid  = threadIdx.x;
    const int lane = tid & 63;
    const int wave = tid >> 6;
    const int wm = wave & 1, wn = wave >> 1;
    const int quad = lane >> 4, l16 = lane & 15;

    f32x4_t acc[4][4];
#pragma unroll
    for (int i = 0; i < 4; ++i)
#pragma unroll
        for (int j = 0; j < 4; ++j) acc[i][j] = (f32x4_t){0.f, 0.f, 0.f, 0.f};

    const f16_t* Pb  = Pm + (size_t)bh * PP * 1024;   // pitch 1024 elements
    const f16_t* vtb = vt + (size_t)bh * EE * PP;
    gemm_bt_core(Pb, 1024, vtb, PP, PP,
                 mt * 128 + wm * 64, nt * 128 + wn * 64, quad, l16, acc);

    const int b = bh >> 1, h = bh & 1;
#pragma unroll
    for (int mi = 0; mi < 4; ++mi)
#pragma unroll
        for (int r = 0; r < 4; ++r) {
            const int p = mt * 128 + wm * 64 + mi * 16 + quad * 4 + r;
#pragma unroll
            for (int ni = 0; ni < 4; ++ni) {
                const int e = nt * 128 + wn * 64 + ni * 16 + l16;
                const int d = e >> 5, t = e & 31;
                out[(((size_t)(b * CC + h * DD + d)) * PP + p) * TT + t] =
                    acc[mi][ni][r];
            }
        }
}

// ---------------------------------------------------------------------------
// Launch. Workspace layout (bytes):
//   [0,   64M)  q   fp16 [b][h][p][e]
//   [64M, 128M) k   fp16 [b][h][p][e]
//   [128M,192M) v   fp16 [b][h][p][e]
//   [192M,256M) vt  fp16 [b][h][e][p]
//   [256M,288M) S   fp32 [bh][i][j]  (P fp16 overlaid, row pitch 1024 elems)
// Total needed: 288 MiB.
// ---------------------------------------------------------------------------
extern "C" void kernel_launch(void* const* d_in, const int* in_sizes, int n_in,
                              void* d_out, int out_size, void* d_ws, size_t ws_size,
                              hipStream_t stream)
{
    const float* x    = (const float*)d_in[0];
    const float* W    = (const float*)d_in[1];
    const float* bias = (const float*)d_in[2];
    float* out = (float*)d_out;

    char* ws = (char*)d_ws;
    const size_t MiB = 1024ull * 1024ull;
    f16_t* q  = (f16_t*)(ws);
    f16_t* k  = (f16_t*)(ws + 64 * MiB);
    f16_t* v  = (f16_t*)(ws + 128 * MiB);
    f16_t* vt = (f16_t*)(ws + 192 * MiB);
    float* S  = (float*)(ws + 256 * MiB);

    proj_kernel<<<dim3(384, 16), dim3(256), 0, stream>>>(x, W, bias, q, k, v);
    vpose_kernel<<<dim3(256, 32), dim3(256), 0, stream>>>(v, vt);
    qk_kernel<<<dim3(16, 32), dim3(256), 0, stream>>>(q, k, S);
    softmax_kernel<<<dim3(4096), dim3(256), 0, stream>>>(S);
    pv_kernel<<<dim3(64, 32), dim3(256), 0, stream>>>((const f16_t*)S, vt, out);
}

// Round 3
// 539.953 us; speedup vs baseline: 1.1562x; 1.1562x over previous
//
#include <hip/hip_runtime.h>

// Problem constants
#define BB 16
#define CC 128
#define PP 512
#define TT 32
#define HH 2
#define DD 64
#define EE 2048        // D*T
#define NPIX 16384     // P*T
#define SCALE 0.125f   // D^-0.5

typedef _Float16 f16_t;
typedef _Float16 f16x8_t __attribute__((ext_vector_type(8)));
typedef float    f32x4_t __attribute__((ext_vector_type(4)));

#define AS_GLOBAL __attribute__((address_space(1)))
#define AS_LDS    __attribute__((address_space(3)))

// Async global->LDS DMA, 16 B per lane. LDS dest is wave-uniform base;
// lane i's 16 B land at base + i*16 (HW-defined, m104/m108).
__device__ __forceinline__ void async_ld16(const void* g, void* l) {
    __builtin_amdgcn_global_load_lds((const AS_GLOBAL void*)g,
                                     (AS_LDS void*)l, 16, 0, 0);
}

// ---------------------------------------------------------------------------
// LDS-staged GEMM core (m97 structure): C(128x128) = A[Mx K] @ Bt[N x K]^T.
// 256 threads / 4 waves; wave = 64x64 (4x4 of 16x16x32 MFMA). BK=32.
// LDS tile layout is K-chunk-major: slot s = chunk*128 + row holds
// row's fp16[chunk*8 .. chunk*8+8). This is contiguous in lane order for
// global_load_lds AND makes each 64-lane ds_read_b128 fragment read
// phase-minimal (verified bank math: 16 lanes/quad cover 8 distinct
// 4-bank groups; 1 KB total = 8 phases = minimum).
// Staging: wave w loads k-chunk w, rows {lane, 64+lane} -> 4 insts/wave/iter.
// MFMA lane mapping (HW-verified): A[m=lane&15][k=quad*8+j],
// B[k=quad*8+j][n=lane&15], D[row=quad*4+reg][col=lane&15].
// ---------------------------------------------------------------------------
__device__ __forceinline__ void gemm_lds_bt(const f16_t* __restrict__ A, int lda,
                                            const f16_t* __restrict__ Bt, int ldb,
                                            int K, int m0, int n0,
                                            f16_t* As, f16_t* Bs,
                                            f32x4_t acc[4][4])
{
    const int tid  = threadIdx.x;
    const int lane = tid & 63;
    const int wave = tid >> 6;
    const int wm = wave & 1, wn = wave >> 1;
    const int quad = lane >> 4, l16 = lane & 15;

    const f16_t* gA0 = A  + (size_t)(m0 + lane)      * lda + wave * 8;
    const f16_t* gA1 = A  + (size_t)(m0 + 64 + lane) * lda + wave * 8;
    const f16_t* gB0 = Bt + (size_t)(n0 + lane)      * ldb + wave * 8;
    const f16_t* gB1 = Bt + (size_t)(n0 + 64 + lane) * ldb + wave * 8;
    f16_t* lA0 = As + (size_t)(wave * 128)      * 8;
    f16_t* lA1 = As + (size_t)(wave * 128 + 64) * 8;
    f16_t* lB0 = Bs + (size_t)(wave * 128)      * 8;
    f16_t* lB1 = Bs + (size_t)(wave * 128 + 64) * 8;

    const int ar = wm * 64 + l16;
    const int br = wn * 64 + l16;

    for (int k0 = 0; k0 < K; k0 += 32) {
        if (k0) __syncthreads();            // prior iter's LDS reads done
        async_ld16(gA0 + k0, lA0);
        async_ld16(gA1 + k0, lA1);
        async_ld16(gB0 + k0, lB0);
        async_ld16(gB1 + k0, lB1);
        __syncthreads();                    // vmcnt(0) drain + barrier

        f16x8_t af[4], bf[4];
#pragma unroll
        for (int mi = 0; mi < 4; ++mi)
            af[mi] = *(const f16x8_t*)(As + (size_t)(quad * 128 + ar + mi * 16) * 8);
#pragma unroll
        for (int ni = 0; ni < 4; ++ni)
            bf[ni] = *(const f16x8_t*)(Bs + (size_t)(quad * 128 + br + ni * 16) * 8);
#pragma unroll
        for (int mi = 0; mi < 4; ++mi)
#pragma unroll
            for (int ni = 0; ni < 4; ++ni)
                acc[mi][ni] = __builtin_amdgcn_mfma_f32_16x16x32_f16(
                    af[mi], bf[ni], acc[mi][ni], 0, 0, 0);
    }
}

// ---------------------------------------------------------------------------
// Kernel 1: QKV projection. Y[o][pix] = sum_c W[o][c]*x[b][c][pix] + bias[o].
// Full K=128 x-tile (128c x 128pix fp32, 64 KB) staged once per block via
// global_load_lds; B-fragments built from LDS (8 x ds_read_b32 + cvt, cheap
// vs the 53 us memory floor). W read direct from global (L2-resident) + cvt.
// grid.x = pt + 128*s  => the 3 s-slices of one x-tile map to the same XCD
// (id%8) for L2 reuse. grid: (384, 16), block 256.
// ---------------------------------------------------------------------------
__global__ __launch_bounds__(256) void proj_kernel(const float* __restrict__ x,
                                                   const float* __restrict__ W,
                                                   const float* __restrict__ bias,
                                                   f16_t* __restrict__ q,
                                                   f16_t* __restrict__ k,
                                                   f16_t* __restrict__ v)
{
    __shared__ float xs[CC * 128];          // [c][pix], 64 KB
    const int b    = blockIdx.y;
    const int s    = blockIdx.x >> 7;       // 0..2
    const int pt   = blockIdx.x & 127;      // 0..127
    const int tid  = threadIdx.x;
    const int lane = tid & 63;
    const int wave = tid >> 6;
    const int wm   = wave & 1, wn = wave >> 1;
    const int quad = lane >> 4, l16 = lane & 15;
    const int pixb = pt * 128;

    const float* xb = x + (size_t)b * CC * NPIX;

    // Stage x tile: 64 insts x 1 KB. inst i covers c = i*2 + lane/32,
    // pix = pixb + (lane&31)*4. LDS elem offset = i*256 + lane*4 (row-major).
#pragma unroll
    for (int ii = 0; ii < 16; ++ii) {
        const int i = wave * 16 + ii;
        const float* g = xb + (size_t)(i * 2 + (lane >> 5)) * NPIX
                            + pixb + (lane & 31) * 4;
        async_ld16(g, xs + i * 256);
    }
    __syncthreads();

    f32x4_t acc[4][4];
#pragma unroll
    for (int i = 0; i < 4; ++i)
#pragma unroll
        for (int j = 0; j < 4; ++j) acc[i][j] = (f32x4_t){0.f, 0.f, 0.f, 0.f};

#pragma unroll
    for (int k0 = 0; k0 < CC; k0 += 32) {
        const int kq = k0 + quad * 8;
        f16x8_t af[4], bf[4];
#pragma unroll
        for (int mi = 0; mi < 4; ++mi) {
            const int o = s * 128 + wm * 64 + mi * 16 + l16;
            const float* wp = W + o * CC + kq;
            const float4 w0 = *(const float4*)wp;
            const float4 w1 = *(const float4*)(wp + 4);
            f16x8_t t;
            t[0] = (_Float16)w0.x; t[1] = (_Float16)w0.y;
            t[2] = (_Float16)w0.z; t[3] = (_Float16)w0.w;
            t[4] = (_Float16)w1.x; t[5] = (_Float16)w1.y;
            t[6] = (_Float16)w1.z; t[7] = (_Float16)w1.w;
            af[mi] = t;
        }
#pragma unroll
        for (int ni = 0; ni < 4; ++ni) {
            const int pl = wn * 64 + ni * 16 + l16;
            f16x8_t t;
#pragma unroll
            for (int j = 0; j < 8; ++j)
                t[j] = (_Float16)xs[(kq + j) * 128 + pl];
            bf[ni] = t;
        }
#pragma unroll
        for (int mi = 0; mi < 4; ++mi)
#pragma unroll
            for (int ni = 0; ni < 4; ++ni)
                acc[mi][ni] = __builtin_amdgcn_mfma_f32_16x16x32_f16(
                    af[mi], bf[ni], acc[mi][ni], 0, 0, 0);
    }

    f16_t* dst = (s == 0) ? q : (s == 1) ? k : v;
#pragma unroll
    for (int mi = 0; mi < 4; ++mi) {
#pragma unroll
        for (int r = 0; r < 4; ++r) {
            const int o_loc = wm * 64 + mi * 16 + quad * 4 + r;
            const int o     = s * 128 + o_loc;
            const float bv  = bias[o];
            const int h = o_loc >> 6, d = o_loc & 63;
#pragma unroll
            for (int ni = 0; ni < 4; ++ni) {
                const int pix = pixb + wn * 64 + ni * 16 + l16;
                const int p = pix >> 5, t = pix & 31;
                const size_t addr =
                    ((size_t)((b * HH + h) * PP + p)) * EE + d * TT + t;
                dst[addr] = (_Float16)(acc[mi][ni][r] + bv);
            }
        }
    }
}

// ---------------------------------------------------------------------------
// Kernel 2: transpose v [bh][p][e] -> vt [bh][e][p] (64x64 LDS tiles).
// ---------------------------------------------------------------------------
__global__ __launch_bounds__(256) void vpose_kernel(const f16_t* __restrict__ v,
                                                    f16_t* __restrict__ vt)
{
    __shared__ unsigned short lds[64][65];
    const int bh   = blockIdx.y;
    const int tile = blockIdx.x;
    const int e0 = (tile & 31) * 64;
    const int p0 = (tile >> 5) * 64;
    const int tid = threadIdx.x;
    const int r0 = tid >> 6;
    const int cc = tid & 63;
    const f16_t* vb  = v  + (size_t)bh * PP * EE;
    f16_t*       vtb = vt + (size_t)bh * EE * PP;
#pragma unroll
    for (int it = 0; it < 16; ++it) {
        const int pl = it * 4 + r0;
        lds[pl][cc] = __builtin_bit_cast(unsigned short,
                          vb[(size_t)(p0 + pl) * EE + e0 + cc]);
    }
    __syncthreads();
#pragma unroll
    for (int it = 0; it < 16; ++it) {
        const int el = it * 4 + r0;
        vtb[(size_t)(e0 + el) * PP + p0 + cc] =
            __builtin_bit_cast(_Float16, lds[cc][el]);
    }
}

// ---------------------------------------------------------------------------
// Kernel 3: S = SCALE * Q @ K^T per (b,h). M=N=512, K=2048.
// grid 512 blocks 1D: bh = id&31 (same bh -> same XCD), tile = id>>5.
// ---------------------------------------------------------------------------
__global__ __launch_bounds__(256) void qk_kernel(const f16_t* __restrict__ q,
                                                 const f16_t* __restrict__ k,
                                                 float* __restrict__ S)
{
    __shared__ f16_t As[128 * 32];
    __shared__ f16_t Bs[128 * 32];
    const int id = blockIdx.x;
    const int bh = id & 31;
    const int tile = id >> 5;               // 0..15
    const int mt = tile & 3, nt = tile >> 2;
    const int tid  = threadIdx.x;
    const int lane = tid & 63;
    const int wave = tid >> 6;
    const int wm = wave & 1, wn = wave >> 1;
    const int quad = lane >> 4, l16 = lane & 15;

    f32x4_t acc[4][4];
#pragma unroll
    for (int i = 0; i < 4; ++i)
#pragma unroll
        for (int j = 0; j < 4; ++j) acc[i][j] = (f32x4_t){0.f, 0.f, 0.f, 0.f};

    const f16_t* qb = q + (size_t)bh * PP * EE;
    const f16_t* kb = k + (size_t)bh * PP * EE;
    gemm_lds_bt(qb, EE, kb, EE, EE, mt * 128, nt * 128, As, Bs, acc);

    float* Sb = S + (size_t)bh * PP * PP;
#pragma unroll
    for (int mi = 0; mi < 4; ++mi)
#pragma unroll
        for (int r = 0; r < 4; ++r) {
            const int row = mt * 128 + wm * 64 + mi * 16 + quad * 4 + r;
#pragma unroll
            for (int ni = 0; ni < 4; ++ni) {
                const int col = nt * 128 + wn * 64 + ni * 16 + l16;
                Sb[(size_t)row * PP + col] = acc[mi][ni][r] * SCALE;
            }
        }
}

// ---------------------------------------------------------------------------
// Kernel 4: row softmax over S, writing normalized P as fp16 overlaid into
// S's storage (row pitch 1024 fp16 = 2048 B). One wave per row.
// ---------------------------------------------------------------------------
__global__ __launch_bounds__(256) void softmax_kernel(float* __restrict__ S)
{
    const int tid  = threadIdx.x;
    const int wave = tid >> 6;
    const int lane = tid & 63;
    const int row  = blockIdx.x * 4 + wave;
    float* rp = S + (size_t)row * PP;

    const float4 a = *(const float4*)(rp + lane * 8);
    const float4 b = *(const float4*)(rp + lane * 8 + 4);

    float m = fmaxf(fmaxf(fmaxf(a.x, a.y), fmaxf(a.z, a.w)),
                    fmaxf(fmaxf(b.x, b.y), fmaxf(b.z, b.w)));
#pragma unroll
    for (int off = 1; off < 64; off <<= 1) m = fmaxf(m, __shfl_xor(m, off, 64));

    float e[8];
    e[0] = expf(a.x - m); e[1] = expf(a.y - m);
    e[2] = expf(a.z - m); e[3] = expf(a.w - m);
    e[4] = expf(b.x - m); e[5] = expf(b.y - m);
    e[6] = expf(b.z - m); e[7] = expf(b.w - m);

    float sum = e[0] + e[1] + e[2] + e[3] + e[4] + e[5] + e[6] + e[7];
#pragma unroll
    for (int off = 1; off < 64; off <<= 1) sum += __shfl_xor(sum, off, 64);
    const float inv = 1.0f / sum;

    __syncthreads();   // order the fp16 stores after all float loads

    f16_t* prow = (f16_t*)rp;
    f16x8_t o;
#pragma unroll
    for (int j = 0; j < 8; ++j) o[j] = (_Float16)(e[j] * inv);
    *(f16x8_t*)(prow + lane * 8) = o;
}

// ---------------------------------------------------------------------------
// Kernel 5: O = P @ V per (b,h) -> out fp32 (b,c,p,t).
// A = P (pitch 1024 fp16), B = vt [e][p]. M=512, N=2048, K=512.
// grid 2048 blocks 1D: bh = id&31, tile = id>>5 (mt = tile&3, nt = tile>>2).
// ---------------------------------------------------------------------------
__global__ __launch_bounds__(256) void pv_kernel(const f16_t* __restrict__ Pm,
                                                 const f16_t* __restrict__ vt,
                                                 float* __restrict__ out)
{
    __shared__ f16_t As[128 * 32];
    __shared__ f16_t Bs[128 * 32];
    const int id = blockIdx.x;
    const int bh = id & 31;
    const int tile = id >> 5;               // 0..63
    const int mt = tile & 3, nt = tile >> 2;
    const int tid  = threadIdx.x;
    const int lane = tid & 63;
    const int wave = tid >> 6;
    const int wm = wave & 1, wn = wave >> 1;
    const int quad = lane >> 4, l16 = lane & 15;

    f32x4_t acc[4][4];
#pragma unroll
    for (int i = 0; i < 4; ++i)
#pragma unroll
        for (int j = 0; j < 4; ++j) acc[i][j] = (f32x4_t){0.f, 0.f, 0.f, 0.f};

    const f16_t* Pb  = Pm + (size_t)bh * PP * 1024;
    const f16_t* vtb = vt + (size_t)bh * EE * PP;
    gemm_lds_bt(Pb, 1024, vtb, PP, PP, mt * 128, nt * 128, As, Bs, acc);

    const int b = bh >> 1, h = bh & 1;
#pragma unroll
    for (int mi = 0; mi < 4; ++mi)
#pragma unroll
        for (int r = 0; r < 4; ++r) {
            const int p = mt * 128 + wm * 64 + mi * 16 + quad * 4 + r;
#pragma unroll
            for (int ni = 0; ni < 4; ++ni) {
                const int e = nt * 128 + wn * 64 + ni * 16 + l16;
                const int d = e >> 5, t = e & 31;
                out[(((size_t)(b * CC + h * DD + d)) * PP + p) * TT + t] =
                    acc[mi][ni][r];
            }
        }
}

// ---------------------------------------------------------------------------
// Workspace layout (bytes):
//   [0,   64M)  q   fp16 [b][h][p][e]
//   [64M, 128M) k   fp16 [b][h][p][e]
//   [128M,192M) v   fp16 [b][h][p][e]
//   [192M,256M) vt  fp16 [b][h][e][p]
//   [256M,288M) S   fp32 [bh][i][j]  (P fp16 overlaid, row pitch 1024 elems)
// ---------------------------------------------------------------------------
extern "C" void kernel_launch(void* const* d_in, const int* in_sizes, int n_in,
                              void* d_out, int out_size, void* d_ws, size_t ws_size,
                              hipStream_t stream)
{
    const float* x    = (const float*)d_in[0];
    const float* W    = (const float*)d_in[1];
    const float* bias = (const float*)d_in[2];
    float* out = (float*)d_out;

    char* ws = (char*)d_ws;
    const size_t MiB = 1024ull * 1024ull;
    f16_t* q  = (f16_t*)(ws);
    f16_t* k  = (f16_t*)(ws + 64 * MiB);
    f16_t* v  = (f16_t*)(ws + 128 * MiB);
    f16_t* vt = (f16_t*)(ws + 192 * MiB);
    float* S  = (float*)(ws + 256 * MiB);

    proj_kernel<<<dim3(384, 16), dim3(256), 0, stream>>>(x, W, bias, q, k, v);
    vpose_kernel<<<dim3(256, 32), dim3(256), 0, stream>>>(v, vt);
    qk_kernel<<<dim3(512), dim3(256), 0, stream>>>(q, k, S);
    softmax_kernel<<<dim3(4096), dim3(256), 0, stream>>>(S);
    pv_kernel<<<dim3(2048), dim3(256), 0, stream>>>((const f16_t*)S, vt, out);
}